// Round 1
// baseline (1650.483 us; speedup 1.0000x reference)
//
#include <hip/hip_runtime.h>
#include <stdint.h>

#define NE    33554432   // 16384*32*64  elements of each (B,W,64) tensor
#define MROWS 524288     // B*W rows of the cat matrix
#define NGRP  8192       // MROWS/64 row-groups

typedef __attribute__((ext_vector_type(8))) short short8;
typedef __attribute__((ext_vector_type(4))) float f32x4;
typedef unsigned short ushort_t;

// ---------- helpers ----------
__device__ __forceinline__ unsigned fenc(float f){
  unsigned u=__float_as_uint(f); return (u&0x80000000u)?~u:(u|0x80000000u);
}
__device__ __forceinline__ float fdec(unsigned u){
  return __uint_as_float((u&0x80000000u)?(u&0x7fffffffu):~u);
}
// observer -> scale/zp  (matches reference fake_quant exactly, fp32 ops)
__device__ __forceinline__ void obs(float mn,float mx,float&s,float&zp){
  mn=fminf(mn,0.f); mx=fmaxf(mx,0.f);
  s=fmaxf((mx-mn)/255.0f,1e-8f);
  zp=fminf(fmaxf(rintf(-128.0f-mn/s),-128.f),127.f);
}
__device__ __forceinline__ float qof(float x,float s,float zp){   // quantized code (as float)
  return fminf(fmaxf(rintf(x/s)+zp,-128.f),127.f);
}
__device__ __forceinline__ float fqv(float x,float s,float zp){   // dequantized value
  return (qof(x,s,zp)-zp)*s;
}
__device__ __forceinline__ void wred(float&mn,float&mx){
  #pragma unroll
  for(int o=32;o;o>>=1){mn=fminf(mn,__shfl_xor(mn,o));mx=fmaxf(mx,__shfl_xor(mx,o));}
}

// U layout (uint minmax slots, order-preserving encoded):
// 0,1 x | 2,3 h | 4,5 c | 6..13 gates(i,f,o,cg) | 14,15 fc | 16,17 ic | 18,19 cn | 20,21 hn
// S layout (float):
// 0-5 sx,zx,sh,zh,sc,zc | 6,7 scat,zcat | 8-15 sW[g],zW[g] | 16-23 sG1[g],zG1[g]
// 24-31 sA2[g],zA2[g] | 32-35 sfc,zfc,sic,zic | 36,37 scn,zcn | 38,39 sct,zct | 40,41 shn,zhn

__global__ void k0_init(unsigned* U){
  int t=threadIdx.x;
  if(t<11){U[2*t]=0xFFFFFFFFu;U[2*t+1]=0u;}
}

__global__ __launch_bounds__(256) void k1_minmax(const float* __restrict__ x,
    const float* __restrict__ h,const float* __restrict__ c,unsigned* U){
  __shared__ float red[8];
  int t=blockIdx.x*256+threadIdx.x, stride=gridDim.x*256;
  int w=threadIdx.x>>6,l=threadIdx.x&63;
  const float4* ps[3]={(const float4*)x,(const float4*)h,(const float4*)c};
  for(int q=0;q<3;q++){
    float mn=3.4e38f,mx=-3.4e38f;
    const float4* p=ps[q];
    for(int e=t;e<NE/4;e+=stride){
      float4 v=p[e];
      mn=fminf(mn,fminf(fminf(v.x,v.y),fminf(v.z,v.w)));
      mx=fmaxf(mx,fmaxf(fmaxf(v.x,v.y),fmaxf(v.z,v.w)));
    }
    wred(mn,mx);
    if(l==0){red[w]=mn;red[4+w]=mx;}
    __syncthreads();
    if(threadIdx.x==0){
      float bmn=fminf(fminf(red[0],red[1]),fminf(red[2],red[3]));
      float bmx=fmaxf(fmaxf(red[4],red[5]),fmaxf(red[6],red[7]));
      atomicMin(&U[2*q],fenc(bmn)); atomicMax(&U[2*q+1],fenc(bmx));
    }
    __syncthreads();
  }
}

// scalars for x/h/c/cat + per-gate weight/bias quantization (single block)
__global__ __launch_bounds__(256) void k2_prep(const float* Wi,const float* bi,
    const float* Wf,const float* bfv,const float* Wo,const float* bo,
    const float* Wcg,const float* bcg,
    const unsigned* U,float* S,ushort_t* Wc,float* bq){
  __shared__ float smn[256],smx[256],sP[4];
  int t=threadIdx.x;
  if(t==0){
    float xmn=fdec(U[0]),xmx=fdec(U[1]),hmn=fdec(U[2]),hmx=fdec(U[3]),cmn=fdec(U[4]),cmx=fdec(U[5]);
    float sx,zx,sh,zh,sc,zc;
    obs(xmn,xmx,sx,zx);obs(hmn,hmx,sh,zh);obs(cmn,cmx,sc,zc);
    S[0]=sx;S[1]=zx;S[2]=sh;S[3]=zh;S[4]=sc;S[5]=zc;
    // cat endpoints via monotonicity of fake_quant
    float cmn2=fminf(fqv(xmn,sx,zx),fqv(hmn,sh,zh));
    float cmx2=fmaxf(fqv(xmx,sx,zx),fqv(hmx,sh,zh));
    float scat,zcat;obs(cmn2,cmx2,scat,zcat);S[6]=scat;S[7]=zcat;
  }
  const float* Wp[4]={Wi,Wf,Wo,Wcg};
  const float* bp[4]={bi,bfv,bo,bcg};
  for(int g=0;g<4;g++){
    float mn=3.4e38f,mx=-3.4e38f;
    for(int i=t;i<8192;i+=256){float v=Wp[g][i];mn=fminf(mn,v);mx=fmaxf(mx,v);}
    smn[t]=mn;smx[t]=mx;__syncthreads();
    for(int ss=128;ss;ss>>=1){
      if(t<ss){smn[t]=fminf(smn[t],smn[t+ss]);smx[t]=fmaxf(smx[t],smx[t+ss]);}
      __syncthreads();
    }
    if(t==0){
      float s_,z_;obs(smn[0],smx[0],s_,z_);
      S[8+2*g]=s_;S[9+2*g]=z_;sP[0]=s_;sP[1]=z_;
      float bmn=3.4e38f,bmx=-3.4e38f;
      for(int i=0;i<64;i++){float v=bp[g][i];bmn=fminf(bmn,v);bmx=fmaxf(bmx,v);}
      float sb,zb;obs(bmn,bmx,sb,zb);sP[2]=sb;sP[3]=zb;
    }
    __syncthreads();
    float s_=sP[0],z_=sP[1],sb=sP[2],zb=sP[3];
    for(int i=t;i<8192;i+=256){
      float cv=qof(Wp[g][i],s_,z_)-z_;                 // centered integer, exact in bf16
      Wc[g*8192+i]=(ushort_t)(__float_as_uint(cv)>>16);
    }
    if(t<64) bq[g*64+t]=fqv(bp[g][t],sb,zb);
    __syncthreads();
  }
}

// quantize: cat -> centered bf16 (in d_out h-half as scratch), c -> int8 codes
__global__ __launch_bounds__(256) void k3_quant(const float* __restrict__ x,
    const float* __restrict__ h,const float* __restrict__ c,
    const float* __restrict__ S,ushort_t* __restrict__ catc,signed char* __restrict__ qc){
  float sx=S[0],zx=S[1],sh=S[2],zh=S[3],sc=S[4],zc=S[5],scat=S[6],zcat=S[7];
  int t=blockIdx.x*256+threadIdx.x, stride=gridDim.x*256;
  const float4* xp=(const float4*)x; const float4* hp=(const float4*)h;
  for(int e=t;e<MROWS*32;e+=stride){      // 32 float4 per 128-wide row
    int row=e>>5,k4=e&31;
    float4 v; float s1,z1;
    if(k4<16){v=xp[row*16+k4];s1=sx;z1=zx;}
    else     {v=hp[row*16+(k4-16)];s1=sh;z1=zh;}
    float c0=qof((qof(v.x,s1,z1)-z1)*s1,scat,zcat)-zcat;
    float c1=qof((qof(v.y,s1,z1)-z1)*s1,scat,zcat)-zcat;
    float c2=qof((qof(v.z,s1,z1)-z1)*s1,scat,zcat)-zcat;
    float c3=qof((qof(v.w,s1,z1)-z1)*s1,scat,zcat)-zcat;
    uint2 o;
    o.x=(__float_as_uint(c0)>>16)|((__float_as_uint(c1)>>16)<<16);
    o.y=(__float_as_uint(c2)>>16)|((__float_as_uint(c3)>>16)<<16);
    ((uint2*)catc)[e]=o;
  }
  const float4* cp=(const float4*)c;
  unsigned* qcp=(unsigned*)qc;
  for(int e=t;e<NE/4;e+=stride){
    float4 v=cp[e];
    int q0=(int)qof(v.x,sc,zc),q1=(int)qof(v.y,sc,zc),q2=(int)qof(v.z,sc,zc),q3=(int)qof(v.w,sc,zc);
    qcp[e]=(q0&0xff)|((q1&0xff)<<8)|((q2&0xff)<<16)|((unsigned)(q3&0xff)<<24);
  }
}

// The workhorse: exact integer GEMM via bf16 MFMA + per-mode epilogue.
// MODE 0: gate pre-act minmax    MODE 1: fc/ic minmax
// MODE 2: c_next_raw minmax      MODE 3: write c_next,q_cn,q_o ; h_raw minmax
template<int MODE>
__global__ __launch_bounds__(256,2) void gemm_pass(const ushort_t* __restrict__ catc,
    const ushort_t* __restrict__ Wc,const float* __restrict__ S,const float* __restrict__ bq,
    const signed char* __restrict__ qc,unsigned* U,float* __restrict__ c_out,
    signed char* __restrict__ qcn,signed char* __restrict__ qo){
  constexpr int GD=(MODE==0)?1:4;
  __shared__ float lds[GD][64][64];          // 64KB for MODE>0 (2 blocks/CU)
  float* red=(float*)lds;                    // aliased scratch, used only after final barrier
  int tid=threadIdx.x,w=tid>>6,l=tid&63,l15=l&15,lq=l>>4;
  float sgp=S[6]*S[8+2*w];                   // s_cat * s_w[gate]
  float sg1=S[16+2*w],zg1=S[17+2*w],sa2=S[24+2*w],za2=S[25+2*w];
  float sc=S[4],zc=S[5];
  float sfc=S[32],zfc=S[33],sic=S[34],zic=S[35];
  float scn=S[36],zcn=S[37],sct=S[38],zct=S[39];
  float so2=S[28],zo2=S[29];
  short8 bf[4][4];
  #pragma unroll
  for(int nt=0;nt<4;nt++)
    #pragma unroll
    for(int ks=0;ks<4;ks++)
      bf[nt][ks]=*(const short8*)(Wc+w*8192+(nt*16+l15)*128+ks*32+lq*8);
  float bqr[4];
  #pragma unroll
  for(int nt=0;nt<4;nt++) bqr[nt]=bq[w*64+nt*16+l15];
  float r0mn=3.4e38f,r0mx=-3.4e38f,r1mn=3.4e38f,r1mx=-3.4e38f;
  for(int gi=0;gi<8;gi++){
    int grp=blockIdx.x*8+gi;
    int rowbase=grp*64;
    #pragma unroll
    for(int mt=0;mt<4;mt++){
      const ushort_t* arow=catc+(rowbase+mt*16+l15)*128;
      short8 af[4];
      #pragma unroll
      for(int ks=0;ks<4;ks++) af[ks]=*(const short8*)(arow+ks*32+lq*8);
      f32x4 acc[4];
      #pragma unroll
      for(int nt=0;nt<4;nt++) acc[nt]=(f32x4){0.f,0.f,0.f,0.f};
      #pragma unroll
      for(int ks=0;ks<4;ks++)
        #pragma unroll
        for(int nt=0;nt<4;nt++)
          acc[nt]=__builtin_amdgcn_mfma_f32_16x16x32_bf16(af[ks],bf[nt][ks],acc[nt],0,0,0);
      #pragma unroll
      for(int nt=0;nt<4;nt++)
        #pragma unroll
        for(int r=0;r<4;r++){
          float v=sgp*acc[nt][r]+bqr[nt];     // exact integer dot * scales + fq(bias)
          if constexpr(MODE==0){ r0mn=fminf(r0mn,v); r0mx=fmaxf(r0mx,v); }
          else{
            float g1=fqv(v,sg1,zg1);
            float a=(w==3)?fminf(fmaxf(g1,-1.f),1.f)
                          :fminf(fmaxf(g1/6.0f+0.5f,0.f),1.f);
            float av=fqv(a,sa2,za2);
            lds[w][mt*16+lq*4+r][nt*16+l15]=av;
          }
        }
    }
    if constexpr(MODE>0){
      __syncthreads();
      #pragma unroll
      for(int i=0;i<16;i++){
        int e=tid+256*i;
        int row=e>>6,col=e&63;
        int gidx=grp*4096+e;
        float ai=lds[0][row][col],afv=lds[1][row][col],acg=lds[3][row][col];
        float cv=((float)qc[gidx]-zc)*sc;
        float fc=afv*cv, ic=ai*acg;
        if constexpr(MODE==1){
          r0mn=fminf(r0mn,fc);r0mx=fmaxf(r0mx,fc);
          r1mn=fminf(r1mn,ic);r1mx=fmaxf(r1mx,ic);
        } else {
          float fcv=fqv(fc,sfc,zfc),icv=fqv(ic,sic,zic);
          float cn=fcv+icv;
          if constexpr(MODE==2){ r0mn=fminf(r0mn,cn);r0mx=fmaxf(r0mx,cn); }
          else{
            float qcf=qof(cn,scn,zcn);
            float cnv=(qcf-zcn)*scn;
            c_out[gidx]=cnv;
            qcn[gidx]=(signed char)(int)qcf;
            float ao=lds[2][row][col];
            float qo_f=fminf(fmaxf(rintf(ao/so2)+zo2,-128.f),127.f);
            qo[gidx]=(signed char)(int)qo_f;
            float ct=fminf(fmaxf(cnv,-1.f),1.f);
            float ctv=fqv(ct,sct,zct);
            float hr=ao*ctv;
            r0mn=fminf(r0mn,hr);r0mx=fmaxf(r0mx,hr);
          }
        }
      }
      __syncthreads();
    }
  }
  if constexpr(MODE==0){
    wred(r0mn,r0mx);
    if(l==0){atomicMin(&U[6+2*w],fenc(r0mn));atomicMax(&U[7+2*w],fenc(r0mx));}
  } else {
    wred(r0mn,r0mx);
    if(l==0){red[w]=r0mn;red[4+w]=r0mx;}
    __syncthreads();
    if(tid==0){
      float mn=fminf(fminf(red[0],red[1]),fminf(red[2],red[3]));
      float mx=fmaxf(fmaxf(red[4],red[5]),fmaxf(red[6],red[7]));
      constexpr int base=(MODE==1)?14:((MODE==2)?18:20);
      atomicMin(&U[base],fenc(mn));atomicMax(&U[base+1],fenc(mx));
    }
    if constexpr(MODE==1){
      __syncthreads();
      wred(r1mn,r1mx);
      if(l==0){red[w]=r1mn;red[4+w]=r1mx;}
      __syncthreads();
      if(tid==0){
        float mn=fminf(fminf(red[0],red[1]),fminf(red[2],red[3]));
        float mx=fmaxf(fmaxf(red[4],red[5]),fmaxf(red[6],red[7]));
        atomicMin(&U[16],fenc(mn));atomicMax(&U[17],fenc(mx));
      }
    }
  }
}

// scalar stages between reduction passes
__global__ void k_post(int stage,const unsigned* U,float* S){
  if(threadIdx.x!=0||blockIdx.x!=0)return;
  if(stage==0){
    for(int g=0;g<4;g++){
      float mn=fdec(U[6+2*g]),mx=fdec(U[7+2*g]);
      float s1,z1;obs(mn,mx,s1,z1);S[16+2*g]=s1;S[17+2*g]=z1;
      float gmn=fqv(mn,s1,z1),gmx=fqv(mx,s1,z1);
      float amn,amx;
      if(g==3){amn=fminf(fmaxf(gmn,-1.f),1.f);amx=fminf(fmaxf(gmx,-1.f),1.f);}
      else{amn=fminf(fmaxf(gmn/6.0f+0.5f,0.f),1.f);amx=fminf(fmaxf(gmx/6.0f+0.5f,0.f),1.f);}
      float s2,z2;obs(amn,amx,s2,z2);S[24+2*g]=s2;S[25+2*g]=z2;
    }
  } else if(stage==1){
    float s,z;
    obs(fdec(U[14]),fdec(U[15]),s,z);S[32]=s;S[33]=z;
    obs(fdec(U[16]),fdec(U[17]),s,z);S[34]=s;S[35]=z;
  } else if(stage==2){
    float mn=fdec(U[18]),mx=fdec(U[19]);
    float s,z;obs(mn,mx,s,z);S[36]=s;S[37]=z;
    float tmn=fminf(fmaxf(fqv(mn,s,z),-1.f),1.f);
    float tmx=fminf(fmaxf(fqv(mx,s,z),-1.f),1.f);
    float s2,z2;obs(tmn,tmx,s2,z2);S[38]=s2;S[39]=z2;
  } else {
    float s,z;obs(fdec(U[20]),fdec(U[21]),s,z);S[40]=s;S[41]=z;
  }
}

__global__ __launch_bounds__(256) void k9_hout(const signed char* __restrict__ qo,
    const signed char* __restrict__ qcn,const float* __restrict__ S,float* __restrict__ hout){
  float so2=S[28],zo2=S[29],scn=S[36],zcn=S[37],sct=S[38],zct=S[39],shn=S[40],zhn=S[41];
  int t=blockIdx.x*256+threadIdx.x,stride=gridDim.x*256;
  const unsigned* op=(const unsigned*)qo; const unsigned* cp=(const unsigned*)qcn;
  float4* hp=(float4*)hout;
  for(int e=t;e<NE/4;e+=stride){
    unsigned uo=op[e],uc=cp[e];
    float4 outv; float* po=&outv.x;
    #pragma unroll
    for(int j=0;j<4;j++){
      int o8=(int)(signed char)((uo>>(8*j))&0xff);
      int c8=(int)(signed char)((uc>>(8*j))&0xff);
      float ao=((float)o8-zo2)*so2;
      float cnv=((float)c8-zcn)*scn;
      float ct=fminf(fmaxf(cnv,-1.f),1.f);
      float ctv=fqv(ct,sct,zct);
      float hr=ao*ctv;
      float qh=qof(hr,shn,zhn);
      po[j]=(qh-zhn)*shn;
    }
    hp[e]=outv;
  }
}

extern "C" void kernel_launch(void* const* d_in,const int* in_sizes,int n_in,
                              void* d_out,int out_size,void* d_ws,size_t ws_size,
                              hipStream_t stream){
  (void)in_sizes;(void)n_in;(void)out_size;(void)ws_size;
  const float* x  =(const float*)d_in[0];
  const float* h  =(const float*)d_in[1];
  const float* c  =(const float*)d_in[2];
  const float* Wi =(const float*)d_in[3];  const float* bi =(const float*)d_in[4];
  const float* Wf =(const float*)d_in[5];  const float* bfv=(const float*)d_in[6];
  const float* Wo =(const float*)d_in[7];  const float* bo =(const float*)d_in[8];
  const float* Wcg=(const float*)d_in[9];  const float* bcg=(const float*)d_in[10];

  char* ws=(char*)d_ws;
  unsigned* U =(unsigned*)ws;                 // 128 B
  float* S    =(float*)(ws+128);              // 256 B
  float* bq   =(float*)(ws+512);              // 1 KB
  ushort_t* Wc=(ushort_t*)(ws+2048);          // 64 KB centered-bf16 weights
  signed char* qc =(signed char*)(ws+(1<<20));    // 32 MB c codes
  signed char* qcn=qc +(size_t)NE;                // 32 MB c_next codes
  signed char* qo =qcn+(size_t)NE;                // 32 MB o-gate codes
  // d_out h-half doubles as cat scratch (exactly NE*4 bytes) until k9 overwrites it
  ushort_t* catc=(ushort_t*)d_out;
  float* c_out=(float*)d_out+NE;
  float* h_out=(float*)d_out;

  k0_init<<<1,64,0,stream>>>(U);
  k1_minmax<<<1024,256,0,stream>>>(x,h,c,U);
  k2_prep<<<1,256,0,stream>>>(Wi,bi,Wf,bfv,Wo,bo,Wcg,bcg,U,S,Wc,bq);
  k3_quant<<<2048,256,0,stream>>>(x,h,c,S,catc,qc);
  gemm_pass<0><<<1024,256,0,stream>>>(catc,Wc,S,bq,qc,U,c_out,qcn,qo);
  k_post<<<1,64,0,stream>>>(0,U,S);
  gemm_pass<1><<<1024,256,0,stream>>>(catc,Wc,S,bq,qc,U,c_out,qcn,qo);
  k_post<<<1,64,0,stream>>>(1,U,S);
  gemm_pass<2><<<1024,256,0,stream>>>(catc,Wc,S,bq,qc,U,c_out,qcn,qo);
  k_post<<<1,64,0,stream>>>(2,U,S);
  gemm_pass<3><<<1024,256,0,stream>>>(catc,Wc,S,bq,qc,U,c_out,qcn,qo);
  k_post<<<1,64,0,stream>>>(3,U,S);
  k9_hout<<<2048,256,0,stream>>>(qo,qcn,S,h_out);
}